// Round 10
// baseline (313.451 us; speedup 1.0000x reference)
//
#include <hip/hip_runtime.h>
#include <hip/hip_bf16.h>
#include <stdint.h>

typedef unsigned short ushort_t;
typedef __attribute__((ext_vector_type(8))) __bf16 bf16x8;
typedef __attribute__((ext_vector_type(8))) short short8;
typedef __attribute__((ext_vector_type(4))) float f32x4;
typedef __attribute__((ext_vector_type(4))) unsigned int uint4v;

// ---- helpers ----------------------------------------------------------------
__device__ __forceinline__ ushort_t f2b(float f) {  // fp32 -> bf16 (RNE)
  union { float f; uint32_t u; } c; c.f = f;
  return (ushort_t)((c.u + 0x7fffu + ((c.u >> 16) & 1u)) >> 16);
}
__device__ __forceinline__ float b2f(ushort_t b) {
  union { float f; uint32_t u; } c; c.u = ((uint32_t)b) << 16;
  return c.f;
}
__device__ __forceinline__ float dot2bf(uint32_t qu, uint32_t ku, float acc) {
  union { uint32_t u; float f; } a, b, c, d;
  a.u = qu << 16; b.u = qu & 0xffff0000u;
  c.u = ku << 16; d.u = ku & 0xffff0000u;
  acc = fmaf(a.f, c.f, acc);
  return fmaf(b.f, d.f, acc);
}

// ---- elementwise f32 -> bf16 ------------------------------------------------
__global__ __launch_bounds__(256) void f32_to_b16(
    const float* __restrict__ in, ushort_t* __restrict__ out) {
  const int i = (blockIdx.x * 256 + threadIdx.x) * 8;
  const f32x4 a = *(const f32x4*)&in[i];
  const f32x4 b = *(const f32x4*)&in[i + 4];
  short8 t;
#pragma unroll
  for (int j = 0; j < 4; j++) { t[j] = (short)f2b(a[j]); t[4 + j] = (short)f2b(b[j]); }
  *(short8*)&out[i] = t;
}

// ---- transpose f32 [K][N] -> bf16 [N][K] ------------------------------------
__global__ __launch_bounds__(256) void transpose_f2b(
    const float* __restrict__ in, ushort_t* __restrict__ out, int K, int N) {
  __shared__ __align__(16) ushort_t tile[64][72];
  const int k0 = blockIdx.x * 64, n0 = blockIdx.y * 64;
  const int tid = threadIdx.x;
#pragma unroll
  for (int i = 0; i < 4; i++) {
    const int idx = i * 256 + tid;
    const int r = idx >> 4, c = (idx & 15) * 4;
    const f32x4 a = *(const f32x4*)&in[(size_t)(k0 + r) * N + n0 + c];
#pragma unroll
    for (int j = 0; j < 4; j++) tile[r][c + j] = f2b(a[j]);
  }
  __syncthreads();
#pragma unroll
  for (int i = 0; i < 16; i++) {
    const int idx = i * 256 + tid;
    const int r = idx >> 6, c = idx & 63;
    out[(size_t)(n0 + r) * K + k0 + c] = tile[c][r];
  }
}

// ---- GEMM: C[M,N] = A[M,K](bf16) * Bt[N,K]^T(bf16) + bias -------------------
// MODE 0: scatter bf16 into q/k/v [B,H,T,D].  MODE 1: f32 row-major out.
// Staging via global_load_lds dwordx4 (LDS dest = base + lane*16, rows 128 B).
// XCD-confining swizzle: each XCD owns 8 consecutive row-panels so the 2 MB
// A chunk stays L2-resident while B streams. Requires gridDim.y==64.
template <int MODE>
__global__ __launch_bounds__(256) void gemm_bt(
    const ushort_t* __restrict__ A, const ushort_t* __restrict__ Bt,
    const float* __restrict__ bias,
    ushort_t* __restrict__ q_out, ushort_t* __restrict__ k_out,
    ushort_t* __restrict__ v_out, float* __restrict__ f_out,
    int M, int N, int K) {
  __shared__ __align__(16) ushort_t Als[128 * 64];
  __shared__ __align__(16) ushort_t Bls[128 * 64];
  const int tid = threadIdx.x;
  const int wave = tid >> 6, lane = tid & 63;
  const int quad = lane >> 4, l15 = lane & 15;
  const int wr = wave >> 1, wc = wave & 1;
  // bijective XCD remap (nbx*64 % 8 == 0 for both grids: 24x64, 8x64)
  const int linear = (int)blockIdx.x + (int)gridDim.x * (int)blockIdx.y;
  const int xcd = linear & 7, chunk = linear >> 3;
  const int by = xcd * 8 + (chunk & 7);   // 8 row-panels per XCD
  const int bx = chunk >> 3;
  const int rowBase = by * 128;
  const int colBase = bx * 128;
  const f32x4 fzero = {0.f, 0.f, 0.f, 0.f};

  f32x4 acc[4][4];
#pragma unroll
  for (int mi = 0; mi < 4; mi++)
#pragma unroll
    for (int ni = 0; ni < 4; ni++) acc[mi][ni] = fzero;

  const int srow = tid >> 3;       // 0..31
  const int scol = (tid & 7) * 8;  // 0,8,...,56 (elements)

  for (int kk = 0; kk < K; kk += 64) {
    __syncthreads();
#pragma unroll
    for (int s = 0; s < 4; s++) {
      const int r = s * 32 + srow;
      __builtin_amdgcn_global_load_lds(
          (const __attribute__((address_space(1))) unsigned int*)
              &A[(size_t)(rowBase + r) * K + kk + scol],
          (__attribute__((address_space(3))) unsigned int*)&Als[r * 64 + scol],
          16, 0, 0);
      __builtin_amdgcn_global_load_lds(
          (const __attribute__((address_space(1))) unsigned int*)
              &Bt[(size_t)(colBase + r) * K + kk + scol],
          (__attribute__((address_space(3))) unsigned int*)&Bls[r * 64 + scol],
          16, 0, 0);
    }
    __syncthreads();
#pragma unroll
    for (int ks = 0; ks < 2; ks++) {
      const int ko = ks * 32 + quad * 8;
      bf16x8 af[4], bfr[4];
#pragma unroll
      for (int mi = 0; mi < 4; mi++)
        af[mi] = *(const bf16x8*)&Als[(wr * 64 + mi * 16 + l15) * 64 + ko];
#pragma unroll
      for (int ni = 0; ni < 4; ni++)
        bfr[ni] = *(const bf16x8*)&Bls[(wc * 64 + ni * 16 + l15) * 64 + ko];
#pragma unroll
      for (int mi = 0; mi < 4; mi++)
#pragma unroll
        for (int ni = 0; ni < 4; ni++)
          acc[mi][ni] = __builtin_amdgcn_mfma_f32_16x16x32_bf16(
              af[mi], bfr[ni], acc[mi][ni], 0, 0, 0);
    }
  }

  if (MODE == 0) {
    const int which = colBase >> 10;
    ushort_t* dst = which == 0 ? q_out : (which == 1 ? k_out : v_out);
    const int h = ((colBase & 1023) >> 6) + wc;
#pragma unroll
    for (int mi = 0; mi < 4; mi++) {
#pragma unroll
      for (int ni = 0; ni < 4; ni++) {
        const int d = ni * 16 + l15;
        const float bv = bias[colBase + wc * 64 + d];
#pragma unroll
        for (int r = 0; r < 4; r++) {
          const int row = rowBase + wr * 64 + mi * 16 + quad * 4 + r;
          const int bidx = row >> 12, t = row & 4095;
          dst[(size_t)((bidx * 16 + h) * 4096 + t) * 64 + d] =
              f2b(acc[mi][ni][r] + bv);
        }
      }
    }
  } else {
#pragma unroll
    for (int mi = 0; mi < 4; mi++) {
#pragma unroll
      for (int ni = 0; ni < 4; ni++) {
        const int col = colBase + wc * 64 + ni * 16 + l15;
        const float bv = bias[col];
#pragma unroll
        for (int r = 0; r < 4; r++) {
          const int row = rowBase + wr * 64 + mi * 16 + quad * 4 + r;
          f_out[(size_t)row * N + col] = acc[mi][ni][r] + bv;
        }
      }
    }
  }
}

// ---- sparse flash attention v11 ---------------------------------------------
// v11 = v9 (r8 winner: 118 us, FETCH 28 MB, VGPR 124, zero spill) restored
// VERBATIM -- r9's T14 pipeline regressed to 134.7 us because the scheduler
// sank the prefetch loads back to their use (VGPR 124->68 signature) and the
// loop-ification added per-tile overhead -- plus ONE new lever: T5 s_setprio
// around both MFMA clusters. Mechanism: 4 blocks/CU sit at different tile
// phases; priority makes the CU scheduler prefer MFMA-issuing waves over
// staging waves of co-resident blocks (guide m191: +4-7% attn; null only for
// single-block lockstep). Delta vs r8 is attributable to setprio alone.
#define LP 72
__global__ __launch_bounds__(256) void sparse_attn(
    const ushort_t* __restrict__ Qb, const ushort_t* __restrict__ Kb,
    const ushort_t* __restrict__ Vb, ushort_t* __restrict__ Y) {
  __shared__ __align__(16) ushort_t Qls[64 * LP];
  // K / Vt / P regions; the first 17408 B are reused as f32 merge scratch
  // after the last dense tile (temporally dead by then).
  __shared__ __align__(16) char smem[(64 * LP + 64 * LP + 4 * 16 * LP) * 2];
  ushort_t* Kls = (ushort_t*)smem;
  ushort_t* Vtls = Kls + 64 * LP;
  ushort_t* Pls = Vtls + 64 * LP;

  const int tid = threadIdx.x;
  const int wave = tid >> 6, lane = tid & 63;
  const int quad = lane >> 4, l15 = lane & 15;

  // XCD-confining + LPT remap: xcd = linear%8 owns 4 head-pairs; within an
  // XCD, qt-major descending (heaviest blocks of all its heads first).
  const int linear = (int)blockIdx.x + 64 * (int)blockIdx.y + 1024 * (int)blockIdx.z;
  const int xcd = linear & 7, slot = linear >> 3;       // slot 0..255
  const int pair = xcd * 4 + (slot & 3);                // (b*16+h) index 0..31
  const int qt = 63 - (slot >> 2);
  const int h = pair & 15, b = pair >> 4;
  const int q0 = qt * 64;
  const size_t headoff = (size_t)pair * 4096 * 64;
  const ushort_t* Qp = Qb + headoff;
  const ushort_t* Kp = Kb + headoff;
  const ushort_t* Vp = Vb + headoff;
  const f32x4 fzero = {0.f, 0.f, 0.f, 0.f};
  const float scale = 0.125f;

#pragma unroll
  for (int i = 0; i < 2; i++) {  // stage Q (kept resident all phases)
    const int idx = i * 256 + tid;
    const int r = idx >> 3, c = (idx & 7) * 8;
    *(short8*)&Qls[r * LP + c] = *(const short8*)&Qp[(size_t)(q0 + r) * 64 + c];
  }
  __syncthreads();
  bf16x8 qf[2];
#pragma unroll
  for (int ks = 0; ks < 2; ks++)
    qf[ks] = *(const bf16x8*)&Qls[(wave * 16 + l15) * LP + ks * 32 + quad * 8];

  f32x4 o[4];
#pragma unroll
  for (int dt = 0; dt < 4; dt++) o[dt] = fzero;
  float mrun[4], lsum[4];
#pragma unroll
  for (int r = 0; r < 4; r++) { mrun[r] = -1e30f; lsum[r] = 0.f; }
  ushort_t* Pw = &Pls[wave * 16 * LP];

  // mode: 0=no mask, 1=causal only, 2=dist<256||dist%128==0, 3=full
  auto dense_tile = [&](int k0, int mode) {
    __syncthreads();
#pragma unroll
    for (int i = 0; i < 2; i++) {  // K [key][d]
      const int idx = i * 256 + tid;
      const int r = idx >> 3, c = (idx & 7) * 8;
      *(short8*)&Kls[r * LP + c] = *(const short8*)&Kp[(size_t)(k0 + r) * 64 + c];
    }
#pragma unroll
    for (int i = 0; i < 2; i++) {  // V transposed [d][key]
      const int idx = i * 256 + tid;
      const int key = idx & 63, dblk = (idx >> 6) * 8;
      short8 vv = *(const short8*)&Vp[(size_t)(k0 + key) * 64 + dblk];
#pragma unroll
      for (int m = 0; m < 8; m++) Vtls[(dblk + m) * LP + key] = (ushort_t)vv[m];
    }
    __syncthreads();

    f32x4 sacc[4];
#pragma unroll
    for (int ni = 0; ni < 4; ni++) sacc[ni] = fzero;
    __builtin_amdgcn_s_setprio(1);   // T5: favor MFMA-issuing waves
#pragma unroll
    for (int ks = 0; ks < 2; ks++) {
      const int ko = ks * 32 + quad * 8;
#pragma unroll
      for (int ni = 0; ni < 4; ni++) {
        bf16x8 kf = *(const bf16x8*)&Kls[(ni * 16 + l15) * LP + ko];
        sacc[ni] = __builtin_amdgcn_mfma_f32_16x16x32_bf16(qf[ks], kf, sacc[ni], 0, 0, 0);
      }
    }
    __builtin_amdgcn_s_setprio(0);

    float p[4][4];
    const int i0 = q0 + wave * 16 + quad * 4;
    if (mode == 0) {
#pragma unroll
      for (int ni = 0; ni < 4; ni++)
#pragma unroll
        for (int r = 0; r < 4; r++) p[ni][r] = sacc[ni][r] * scale;
    } else {
#pragma unroll
      for (int ni = 0; ni < 4; ni++) {
        const int j = k0 + ni * 16 + l15;
#pragma unroll
        for (int r = 0; r < 4; r++) {
          const int dist = i0 + r - j;
          bool ok;
          if (mode == 1)      ok = dist >= 0;
          else if (mode == 2) ok = (dist < 256) || ((dist & 127) == 0);
          else                ok = (dist >= 0) &&
                                   ((dist < 256) || ((dist & 127) == 0) || (j < 16));
          p[ni][r] = ok ? sacc[ni][r] * scale : -1e30f;
        }
      }
    }

    float alpha[4];
#pragma unroll
    for (int r = 0; r < 4; r++) {
      float m = fmaxf(fmaxf(p[0][r], p[1][r]), fmaxf(p[2][r], p[3][r]));
      m = fmaxf(m, __shfl_xor(m, 1));
      m = fmaxf(m, __shfl_xor(m, 2));
      m = fmaxf(m, __shfl_xor(m, 4));
      m = fmaxf(m, __shfl_xor(m, 8));
      const float mnew = fmaxf(mrun[r], m);
      alpha[r] = __expf(mrun[r] - mnew);
      mrun[r] = mnew;
      float rs = 0.f;
#pragma unroll
      for (int ni = 0; ni < 4; ni++) {
        const float e = __expf(p[ni][r] - mnew);
        p[ni][r] = e;
        rs += e;
      }
      rs += __shfl_xor(rs, 1);
      rs += __shfl_xor(rs, 2);
      rs += __shfl_xor(rs, 4);
      rs += __shfl_xor(rs, 8);
      lsum[r] = lsum[r] * alpha[r] + rs;
    }
#pragma unroll
    for (int dt = 0; dt < 4; dt++)
#pragma unroll
      for (int r = 0; r < 4; r++) o[dt][r] *= alpha[r];

#pragma unroll
    for (int ni = 0; ni < 4; ni++)
#pragma unroll
      for (int r = 0; r < 4; r++)
        Pw[(quad * 4 + r) * LP + ni * 16 + l15] = f2b(p[ni][r]);
    __syncthreads();

    __builtin_amdgcn_s_setprio(1);   // T5: PV cluster
#pragma unroll
    for (int ks = 0; ks < 2; ks++) {
      const int ko = ks * 32 + quad * 8;
      bf16x8 pf = *(const bf16x8*)&Pw[l15 * LP + ko];
#pragma unroll
      for (int dt = 0; dt < 4; dt++) {
        bf16x8 vf = *(const bf16x8*)&Vtls[(dt * 16 + l15) * LP + ko];
        o[dt] = __builtin_amdgcn_mfma_f32_16x16x32_bf16(pf, vf, o[dt], 0, 0, 0);
      }
    }
    __builtin_amdgcn_s_setprio(0);
  };

  if (qt < 6) {
    for (int kt = 0; kt <= qt; kt++) dense_tile(kt * 64, 3);
  } else {
    dense_tile(0, 3);                 // global + strided j<64
    dense_tile((qt - 4) * 64, 2);     // window edge + s=2 diag
    dense_tile((qt - 3) * 64, 0);
    dense_tile((qt - 2) * 64, 0);
    dense_tile((qt - 1) * 64, 0);
    dense_tile(qt * 64, 1);           // causal diag

    // ---- strided phase: per-wave, barrier-free, register-resident ----------
    // key j = i - 128s, blocks [k0s, k0s+64), k0s >= 64.
    // Lane (quad,l15) owns key/q row (wave*16+l15), dims quad*16..+16:
    // exactly the layout K/V rows arrive in -> no per-level redistribution.
    const int rowl = wave * 16 + l15;
    const uint4v qv0 = *(const uint4v*)&Qls[rowl * LP + quad * 16];
    const uint4v qv1 = *(const uint4v*)&Qls[rowl * LP + quad * 16 + 8];
    const ushort_t* Kr = Kp + (size_t)rowl * 64 + quad * 16;
    const ushort_t* Vr = Vp + (size_t)rowl * 64 + quad * 16;

    float ms = -1e30f, ls = 0.f;
    f32x4 os4[4];
#pragma unroll
    for (int c = 0; c < 4; c++) os4[c] = fzero;

    auto sproc = [&](uint4v ka0, uint4v ka1, uint4v va0, uint4v va1) {
      float sd = 0.f;
#pragma unroll
      for (int m2 = 0; m2 < 4; m2++) {
        sd = dot2bf(qv0[m2], ka0[m2], sd);
        sd = dot2bf(qv1[m2], ka1[m2], sd);
      }
      sd += __shfl_xor(sd, 16);
      sd += __shfl_xor(sd, 32);
      const float sig = sd * scale;
      const float mnew = fmaxf(ms, sig);
      const float al = __expf(ms - mnew);
      const float e = __expf(sig - mnew);
      ms = mnew;
      ls = ls * al + e;
#pragma unroll
      for (int m2 = 0; m2 < 4; m2++) {
        union { uint32_t u; float f; } va, vb, vc, vd;
        va.u = va0[m2] << 16;          // dim 2*m2
        vb.u = va0[m2] & 0xffff0000u;  // dim 2*m2+1
        vc.u = va1[m2] << 16;          // dim 8+2*m2
        vd.u = va1[m2] & 0xffff0000u;  // dim 8+2*m2+1
        const int d0 = 2 * m2, d1 = 2 * m2 + 1;
        os4[d0 >> 2][d0 & 3] = fmaf(os4[d0 >> 2][d0 & 3], al, e * va.f);
        os4[d1 >> 2][d1 & 3] = fmaf(os4[d1 >> 2][d1 & 3], al, e * vb.f);
        os4[(d0 + 8) >> 2][d0 & 3] = fmaf(os4[(d0 + 8) >> 2][d0 & 3], al, e * vc.f);
        os4[(d1 + 8) >> 2][d1 & 3] = fmaf(os4[(d1 + 8) >> 2][d1 & 3], al, e * vd.f);
      }
    };

    int k0s = q0 - 384;
    if (k0s >= 64) {
      uint4v ka0 = *(const uint4v*)(Kr + (size_t)k0s * 64);
      uint4v ka1 = *(const uint4v*)(Kr + (size_t)k0s * 64 + 8);
      uint4v va0 = *(const uint4v*)(Vr + (size_t)k0s * 64);
      uint4v va1 = *(const uint4v*)(Vr + (size_t)k0s * 64 + 8);
      while (true) {
        const int nxt = k0s - 128;
        uint4v kb0, kb1, vb0, vb1;
        if (nxt >= 64) {  // depth-1 prefetch: latency hides under sproc VALU
          kb0 = *(const uint4v*)(Kr + (size_t)nxt * 64);
          kb1 = *(const uint4v*)(Kr + (size_t)nxt * 64 + 8);
          vb0 = *(const uint4v*)(Vr + (size_t)nxt * 64);
          vb1 = *(const uint4v*)(Vr + (size_t)nxt * 64 + 8);
        }
        sproc(ka0, ka1, va0, va1);
        if (nxt < 64) break;
        ka0 = kb0; ka1 = kb1; va0 = vb0; va1 = vb1;
        k0s = nxt;
      }
    }

    // ---- merge strided state into dense state (once per block) -------------
    // scratch aliases Kls/Vtls: make sure every wave finished its last dense
    // tile's LDS reads before any wave overwrites the region.
    __syncthreads();
    float* scr = (float*)smem + wave * (16 * 68);  // [16 rows][68 f32] per wave
#pragma unroll
    for (int c = 0; c < 4; c++)
      *(f32x4*)&scr[l15 * 68 + quad * 16 + c * 4] = os4[c];
    asm volatile("s_waitcnt lgkmcnt(0)" ::: "memory");
    __builtin_amdgcn_wave_barrier();
#pragma unroll
    for (int r = 0; r < 4; r++) {
      const float ms_r = __shfl(ms, quad * 4 + r);
      const float ls_r = __shfl(ls, quad * 4 + r);
      const float M = fmaxf(mrun[r], ms_r);
      const float ea = __expf(mrun[r] - M);
      const float eb = __expf(ms_r - M);  // == 0 when no strided levels ran
      lsum[r] = lsum[r] * ea + ls_r * eb;
#pragma unroll
      for (int dt = 0; dt < 4; dt++)
        o[dt][r] = o[dt][r] * ea + scr[(quad * 4 + r) * 68 + dt * 16 + l15] * eb;
    }
  }

#pragma unroll
  for (int dt = 0; dt < 4; dt++) {
#pragma unroll
    for (int r = 0; r < 4; r++) {
      const int t = q0 + wave * 16 + quad * 4 + r;
      const int c = h * 64 + dt * 16 + l15;
      Y[(size_t)(b * 4096 + t) * 1024 + c] = f2b(o[dt][r] / lsum[r]);
    }
  }
}

// ---- launch -----------------------------------------------------------------
static const void* by_size(void* const* d_in, const int* in_sizes, int n_in,
                           int want, int fallback_idx) {
  for (int i = 0; i < n_in; i++)
    if (in_sizes[i] == want) return d_in[i];
  return d_in[fallback_idx];
}

extern "C" void kernel_launch(void* const* d_in, const int* in_sizes, int n_in,
                              void* d_out, int out_size, void* d_ws,
                              size_t ws_size, hipStream_t stream) {
  const float* x      = (const float*)by_size(d_in, in_sizes, n_in, 8388608, 0);
  const float* w_qkv  = (const float*)by_size(d_in, in_sizes, n_in, 3145728, 1);
  const float* b_qkv  = (const float*)by_size(d_in, in_sizes, n_in, 3072, 2);
  const float* w_proj = (const float*)by_size(d_in, in_sizes, n_in, 1048576, 3);
  const float* b_proj = (const float*)by_size(d_in, in_sizes, n_in, 1024, 4);
  float* out = (float*)d_out;                     // [2,4096,1024] f32
  char* ws = (char*)d_ws;
  ushort_t* wqkvT  = (ushort_t*)(ws);             //  6.3 MB bf16 [3072,1024]
  ushort_t* wprojT = (ushort_t*)(ws + 6291456);   //  2.1 MB bf16 [1024,1024]
  ushort_t* qb     = (ushort_t*)(ws + 8388608);   // 16.8 MB bf16 [B,H,T,D]
  ushort_t* kb     = (ushort_t*)(ws + 25165824);
  ushort_t* vb     = (ushort_t*)(ws + 41943040);
  ushort_t* yb     = (ushort_t*)(ws + 58720256);  // 16.8 MB bf16 [8192,1024]
  ushort_t* xb     = yb;  // x-bf16 aliases yb: dead before attention writes yb

  if (ws_size < 75497472) return;  // proven satisfied

  f32_to_b16<<<4096, 256, 0, stream>>>(x, xb);
  transpose_f2b<<<dim3(16, 48), 256, 0, stream>>>(w_qkv, wqkvT, 1024, 3072);
  transpose_f2b<<<dim3(16, 16), 256, 0, stream>>>(w_proj, wprojT, 1024, 1024);
  gemm_bt<0><<<dim3(24, 64), 256, 0, stream>>>(
      xb, wqkvT, b_qkv, qb, kb, vb, nullptr, 8192, 3072, 1024);
  sparse_attn<<<dim3(64, 16, 2), 256, 0, stream>>>(qb, kb, vb, yb);
  gemm_bt<1><<<dim3(8, 64), 256, 0, stream>>>(
      yb, wprojT, b_proj, nullptr, nullptr, nullptr, out, 8192, 1024, 1024);
}

// Round 11
// 302.611 us; speedup vs baseline: 1.0358x; 1.0358x over previous
//
#include <hip/hip_runtime.h>
#include <hip/hip_bf16.h>
#include <stdint.h>

typedef unsigned short ushort_t;
typedef __attribute__((ext_vector_type(8))) __bf16 bf16x8;
typedef __attribute__((ext_vector_type(8))) short short8;
typedef __attribute__((ext_vector_type(4))) float f32x4;
typedef __attribute__((ext_vector_type(4))) unsigned int uint4v;

// ---- helpers ----------------------------------------------------------------
__device__ __forceinline__ ushort_t f2b(float f) {  // fp32 -> bf16 (RNE)
  union { float f; uint32_t u; } c; c.f = f;
  return (ushort_t)((c.u + 0x7fffu + ((c.u >> 16) & 1u)) >> 16);
}
__device__ __forceinline__ float b2f(ushort_t b) {
  union { float f; uint32_t u; } c; c.u = ((uint32_t)b) << 16;
  return c.f;
}
__device__ __forceinline__ float dot2bf(uint32_t qu, uint32_t ku, float acc) {
  union { uint32_t u; float f; } a, b, c, d;
  a.u = qu << 16; b.u = qu & 0xffff0000u;
  c.u = ku << 16; d.u = ku & 0xffff0000u;
  acc = fmaf(a.f, c.f, acc);
  return fmaf(b.f, d.f, acc);
}

// ---- elementwise f32 -> bf16 ------------------------------------------------
__global__ __launch_bounds__(256) void f32_to_b16(
    const float* __restrict__ in, ushort_t* __restrict__ out) {
  const int i = (blockIdx.x * 256 + threadIdx.x) * 8;
  const f32x4 a = *(const f32x4*)&in[i];
  const f32x4 b = *(const f32x4*)&in[i + 4];
  short8 t;
#pragma unroll
  for (int j = 0; j < 4; j++) { t[j] = (short)f2b(a[j]); t[4 + j] = (short)f2b(b[j]); }
  *(short8*)&out[i] = t;
}

// ---- transpose f32 [K][N] -> bf16 [N][K] ------------------------------------
__global__ __launch_bounds__(256) void transpose_f2b(
    const float* __restrict__ in, ushort_t* __restrict__ out, int K, int N) {
  __shared__ __align__(16) ushort_t tile[64][72];
  const int k0 = blockIdx.x * 64, n0 = blockIdx.y * 64;
  const int tid = threadIdx.x;
#pragma unroll
  for (int i = 0; i < 4; i++) {
    const int idx = i * 256 + tid;
    const int r = idx >> 4, c = (idx & 15) * 4;
    const f32x4 a = *(const f32x4*)&in[(size_t)(k0 + r) * N + n0 + c];
#pragma unroll
    for (int j = 0; j < 4; j++) tile[r][c + j] = f2b(a[j]);
  }
  __syncthreads();
#pragma unroll
  for (int i = 0; i < 16; i++) {
    const int idx = i * 256 + tid;
    const int r = idx >> 6, c = idx & 63;
    out[(size_t)(n0 + r) * K + k0 + c] = tile[c][r];
  }
}

// ---- GEMM: C[M,N] = A[M,K](bf16) * Bt[N,K]^T(bf16) + bias -------------------
// MODE 0: scatter bf16 into q/k/v [B,H,T,D].  MODE 1: f32 row-major out.
// Staging via global_load_lds dwordx4 (LDS dest = base + lane*16, rows 128 B).
// XCD-confining swizzle: each XCD owns 8 consecutive row-panels so the 2 MB
// A chunk stays L2-resident while B streams. Requires gridDim.y==64.
template <int MODE>
__global__ __launch_bounds__(256) void gemm_bt(
    const ushort_t* __restrict__ A, const ushort_t* __restrict__ Bt,
    const float* __restrict__ bias,
    ushort_t* __restrict__ q_out, ushort_t* __restrict__ k_out,
    ushort_t* __restrict__ v_out, float* __restrict__ f_out,
    int M, int N, int K) {
  __shared__ __align__(16) ushort_t Als[128 * 64];
  __shared__ __align__(16) ushort_t Bls[128 * 64];
  const int tid = threadIdx.x;
  const int wave = tid >> 6, lane = tid & 63;
  const int quad = lane >> 4, l15 = lane & 15;
  const int wr = wave >> 1, wc = wave & 1;
  // bijective XCD remap (nbx*64 % 8 == 0 for both grids: 24x64, 8x64)
  const int linear = (int)blockIdx.x + (int)gridDim.x * (int)blockIdx.y;
  const int xcd = linear & 7, chunk = linear >> 3;
  const int by = xcd * 8 + (chunk & 7);   // 8 row-panels per XCD
  const int bx = chunk >> 3;
  const int rowBase = by * 128;
  const int colBase = bx * 128;
  const f32x4 fzero = {0.f, 0.f, 0.f, 0.f};

  f32x4 acc[4][4];
#pragma unroll
  for (int mi = 0; mi < 4; mi++)
#pragma unroll
    for (int ni = 0; ni < 4; ni++) acc[mi][ni] = fzero;

  const int srow = tid >> 3;       // 0..31
  const int scol = (tid & 7) * 8;  // 0,8,...,56 (elements)

  for (int kk = 0; kk < K; kk += 64) {
    __syncthreads();
#pragma unroll
    for (int s = 0; s < 4; s++) {
      const int r = s * 32 + srow;
      __builtin_amdgcn_global_load_lds(
          (const __attribute__((address_space(1))) unsigned int*)
              &A[(size_t)(rowBase + r) * K + kk + scol],
          (__attribute__((address_space(3))) unsigned int*)&Als[r * 64 + scol],
          16, 0, 0);
      __builtin_amdgcn_global_load_lds(
          (const __attribute__((address_space(1))) unsigned int*)
              &Bt[(size_t)(colBase + r) * K + kk + scol],
          (__attribute__((address_space(3))) unsigned int*)&Bls[r * 64 + scol],
          16, 0, 0);
    }
    __syncthreads();
#pragma unroll
    for (int ks = 0; ks < 2; ks++) {
      const int ko = ks * 32 + quad * 8;
      bf16x8 af[4], bfr[4];
#pragma unroll
      for (int mi = 0; mi < 4; mi++)
        af[mi] = *(const bf16x8*)&Als[(wr * 64 + mi * 16 + l15) * 64 + ko];
#pragma unroll
      for (int ni = 0; ni < 4; ni++)
        bfr[ni] = *(const bf16x8*)&Bls[(wc * 64 + ni * 16 + l15) * 64 + ko];
#pragma unroll
      for (int mi = 0; mi < 4; mi++)
#pragma unroll
        for (int ni = 0; ni < 4; ni++)
          acc[mi][ni] = __builtin_amdgcn_mfma_f32_16x16x32_bf16(
              af[mi], bfr[ni], acc[mi][ni], 0, 0, 0);
    }
  }

  if (MODE == 0) {
    const int which = colBase >> 10;
    ushort_t* dst = which == 0 ? q_out : (which == 1 ? k_out : v_out);
    const int h = ((colBase & 1023) >> 6) + wc;
#pragma unroll
    for (int mi = 0; mi < 4; mi++) {
#pragma unroll
      for (int ni = 0; ni < 4; ni++) {
        const int d = ni * 16 + l15;
        const float bv = bias[colBase + wc * 64 + d];
#pragma unroll
        for (int r = 0; r < 4; r++) {
          const int row = rowBase + wr * 64 + mi * 16 + quad * 4 + r;
          const int bidx = row >> 12, t = row & 4095;
          dst[(size_t)((bidx * 16 + h) * 4096 + t) * 64 + d] =
              f2b(acc[mi][ni][r] + bv);
        }
      }
    }
  } else {
#pragma unroll
    for (int mi = 0; mi < 4; mi++) {
#pragma unroll
      for (int ni = 0; ni < 4; ni++) {
        const int col = colBase + wc * 64 + ni * 16 + l15;
        const float bv = bias[col];
#pragma unroll
        for (int r = 0; r < 4; r++) {
          const int row = rowBase + wr * 64 + mi * 16 + quad * 4 + r;
          f_out[(size_t)row * N + col] = acc[mi][ni][r] + bv;
        }
      }
    }
  }
}

// ---- sparse flash attention v12 ---------------------------------------------
// v12 = v9 compute core (r8 winner, 118 us; setprio removed: r10 measured
// null) restructured to TWO adjacent q-tiles per 512-thread/8-wave block.
// Adjacent q-tiles qt,qt+1 share 5 of 7 dense K/V tiles: staging the union
// once cuts staging volume and barriers per output by ~42%. Waves 0-3 compute
// q-tile qt (wq=0), waves 4-7 compute qt+1 (wq=1); per-tile mask mode chosen
// per wave-group (mode<0 = group idles through compute, barriers stay
// unconditional). LDS 55296 B -> 2 blocks/CU x 8 waves = 16 waves/CU, same
// wave count and VGPR budget as r8. Strided phase/merge are per-wave and
// port mechanically (wl = wave&3, per-group q0).
#define LP 72
__global__ __launch_bounds__(512) void sparse_attn(
    const ushort_t* __restrict__ Qb, const ushort_t* __restrict__ Kb,
    const ushort_t* __restrict__ Vb, ushort_t* __restrict__ Y) {
  __shared__ __align__(16) ushort_t Qls[128 * LP];
  // K | Vt | P regions; whole region reused as f32 merge scratch after the
  // last dense tile (8 waves x 16 x 68 f32 = 34816 B <= 36864 B).
  __shared__ __align__(16) char smem[(64 * LP + 64 * LP + 128 * LP) * 2];
  ushort_t* Kls = (ushort_t*)smem;
  ushort_t* Vtls = Kls + 64 * LP;
  ushort_t* Pls = Vtls + 64 * LP;

  const int tid = threadIdx.x;
  const int wave = tid >> 6, lane = tid & 63;
  const int quad = lane >> 4, l15 = lane & 15;
  const int wq = wave >> 2, wl = wave & 3;  // q-tile group, wave-in-group

  // XCD-confining + LPT remap: xcd = linear%8 owns 4 head-pairs; within an
  // XCD, pair-index descending (heaviest q-tiles of all its heads first).
  const int linear = (int)blockIdx.x + 32 * (int)blockIdx.y + 512 * (int)blockIdx.z;
  const int xcd = linear & 7, slot = linear >> 3;   // slot 0..127
  const int pr = xcd * 4 + (slot & 3);              // (b*16+h) index 0..31
  const int q0t = 2 * (31 - (slot >> 2));           // even q-tile, heavy first
  const int q1t = q0t + 1;
  const int h = pr & 15, b = pr >> 4;
  const int q0 = (q0t + wq) * 64;                   // this wave-group's q-base
  const size_t headoff = (size_t)pr * 4096 * 64;
  const ushort_t* Qp = Qb + headoff;
  const ushort_t* Kp = Kb + headoff;
  const ushort_t* Vp = Vb + headoff;
  const f32x4 fzero = {0.f, 0.f, 0.f, 0.f};
  const float scale = 0.125f;

#pragma unroll
  for (int i = 0; i < 2; i++) {  // stage Q: 128 contiguous rows (both q-tiles)
    const int idx = i * 512 + tid;
    const int r = idx >> 3, c = (idx & 7) * 8;
    *(short8*)&Qls[r * LP + c] = *(const short8*)&Qp[(size_t)(q0t * 64 + r) * 64 + c];
  }
  __syncthreads();
  bf16x8 qf[2];
#pragma unroll
  for (int ks = 0; ks < 2; ks++)
    qf[ks] = *(const bf16x8*)&Qls[(wq * 64 + wl * 16 + l15) * LP + ks * 32 + quad * 8];

  f32x4 o[4];
#pragma unroll
  for (int dt = 0; dt < 4; dt++) o[dt] = fzero;
  float mrun[4], lsum[4];
#pragma unroll
  for (int r = 0; r < 4; r++) { mrun[r] = -1e30f; lsum[r] = 0.f; }
  ushort_t* Pw = &Pls[wave * 16 * LP];

  // mode: -1=skip, 0=no mask, 1=causal only, 2=dist<256||dist%128==0, 3=full
  auto dense_tile = [&](int k0, int modeA, int modeB) {
    const int mode = (wq == 0) ? modeA : modeB;
    __syncthreads();  // prior tile's LDS reads complete
    {  // K [key][d]: 512 threads cover 64 rows x 8 chunks in one pass
      const int r = tid >> 3, c = (tid & 7) * 8;
      *(short8*)&Kls[r * LP + c] = *(const short8*)&Kp[(size_t)(k0 + r) * 64 + c];
    }
    {  // V transposed [d][key]: one short8 per thread
      const int key = tid & 63, dblk = (tid >> 6) * 8;
      short8 vv = *(const short8*)&Vp[(size_t)(k0 + key) * 64 + dblk];
#pragma unroll
      for (int m = 0; m < 8; m++) Vtls[(dblk + m) * LP + key] = (ushort_t)vv[m];
    }
    __syncthreads();  // staging visible

    float p[4][4];
    if (mode >= 0) {
      f32x4 sacc[4];
#pragma unroll
      for (int ni = 0; ni < 4; ni++) sacc[ni] = fzero;
#pragma unroll
      for (int ks = 0; ks < 2; ks++) {
        const int ko = ks * 32 + quad * 8;
#pragma unroll
        for (int ni = 0; ni < 4; ni++) {
          bf16x8 kf = *(const bf16x8*)&Kls[(ni * 16 + l15) * LP + ko];
          sacc[ni] = __builtin_amdgcn_mfma_f32_16x16x32_bf16(qf[ks], kf, sacc[ni], 0, 0, 0);
        }
      }

      const int i0 = q0 + wl * 16 + quad * 4;
      if (mode == 0) {
#pragma unroll
        for (int ni = 0; ni < 4; ni++)
#pragma unroll
          for (int r = 0; r < 4; r++) p[ni][r] = sacc[ni][r] * scale;
      } else {
#pragma unroll
        for (int ni = 0; ni < 4; ni++) {
          const int j = k0 + ni * 16 + l15;
#pragma unroll
          for (int r = 0; r < 4; r++) {
            const int dist = i0 + r - j;
            bool ok;
            if (mode == 1)      ok = dist >= 0;
            else if (mode == 2) ok = (dist < 256) || ((dist & 127) == 0);
            else                ok = (dist >= 0) &&
                                     ((dist < 256) || ((dist & 127) == 0) || (j < 16));
            p[ni][r] = ok ? sacc[ni][r] * scale : -1e30f;
          }
        }
      }

      float alpha[4];
#pragma unroll
      for (int r = 0; r < 4; r++) {
        float m = fmaxf(fmaxf(p[0][r], p[1][r]), fmaxf(p[2][r], p[3][r]));
        m = fmaxf(m, __shfl_xor(m, 1));
        m = fmaxf(m, __shfl_xor(m, 2));
        m = fmaxf(m, __shfl_xor(m, 4));
        m = fmaxf(m, __shfl_xor(m, 8));
        const float mnew = fmaxf(mrun[r], m);
        alpha[r] = __expf(mrun[r] - mnew);
        mrun[r] = mnew;
        float rs = 0.f;
#pragma unroll
        for (int ni = 0; ni < 4; ni++) {
          const float e = __expf(p[ni][r] - mnew);
          p[ni][r] = e;
          rs += e;
        }
        rs += __shfl_xor(rs, 1);
        rs += __shfl_xor(rs, 2);
        rs += __shfl_xor(rs, 4);
        rs += __shfl_xor(rs, 8);
        lsum[r] = lsum[r] * alpha[r] + rs;
      }
#pragma unroll
      for (int dt = 0; dt < 4; dt++)
#pragma unroll
        for (int r = 0; r < 4; r++) o[dt][r] *= alpha[r];

#pragma unroll
      for (int ni = 0; ni < 4; ni++)
#pragma unroll
        for (int r = 0; r < 4; r++)
          Pw[(quad * 4 + r) * LP + ni * 16 + l15] = f2b(p[ni][r]);
    }
    __syncthreads();  // unconditional: all 8 waves rendezvous

    if (mode >= 0) {
#pragma unroll
      for (int ks = 0; ks < 2; ks++) {
        const int ko = ks * 32 + quad * 8;
        bf16x8 pf = *(const bf16x8*)&Pw[l15 * LP + ko];
#pragma unroll
        for (int dt = 0; dt < 4; dt++) {
          bf16x8 vf = *(const bf16x8*)&Vtls[(dt * 16 + l15) * LP + ko];
          o[dt] = __builtin_amdgcn_mfma_f32_16x16x32_bf16(pf, vf, o[dt], 0, 0, 0);
        }
      }
    }
  };

  if (q1t < 6) {
    // light pairs (q0t in {0,2,4}): all tiles full-mask; A skips kt>q0t
    for (int kt = 0; kt <= q1t; kt++)
      dense_tile(kt * 64, kt <= q0t ? 3 : -1, 3);
  } else {
    dense_tile(0, 3, 3);  // global + in-tile strided for both groups
    for (int kt = q0t - 4; kt <= q0t + 1; kt++) {
      const int mA = (kt == q0t - 4) ? 2
                   : (kt < q0t) ? 0 : (kt == q0t) ? 1 : -1;
      const int mB = (kt == q0t - 4) ? -1
                   : (kt == q0t - 3) ? 2 : (kt <= q0t) ? 0 : 1;
      dense_tile(kt * 64, mA, mB);
    }

    // ---- strided phase: per-wave, barrier-free, register-resident ----------
    // key j = i - 128s, blocks [k0s, k0s+64), k0s >= 64. Lane (quad,l15)
    // owns q/key row (wl*16+l15) of its group's q-tile, dims quad*16..+16.
    const int rowl = wl * 16 + l15;
    const uint4v qv0 = *(const uint4v*)&Qls[(wq * 64 + rowl) * LP + quad * 16];
    const uint4v qv1 = *(const uint4v*)&Qls[(wq * 64 + rowl) * LP + quad * 16 + 8];
    const ushort_t* Kr = Kp + (size_t)rowl * 64 + quad * 16;
    const ushort_t* Vr = Vp + (size_t)rowl * 64 + quad * 16;

    float ms = -1e30f, ls = 0.f;
    f32x4 os4[4];
#pragma unroll
    for (int c = 0; c < 4; c++) os4[c] = fzero;

    auto sproc = [&](uint4v ka0, uint4v ka1, uint4v va0, uint4v va1) {
      float sd = 0.f;
#pragma unroll
      for (int m2 = 0; m2 < 4; m2++) {
        sd = dot2bf(qv0[m2], ka0[m2], sd);
        sd = dot2bf(qv1[m2], ka1[m2], sd);
      }
      sd += __shfl_xor(sd, 16);
      sd += __shfl_xor(sd, 32);
      const float sig = sd * scale;
      const float mnew = fmaxf(ms, sig);
      const float al = __expf(ms - mnew);
      const float e = __expf(sig - mnew);
      ms = mnew;
      ls = ls * al + e;
#pragma unroll
      for (int m2 = 0; m2 < 4; m2++) {
        union { uint32_t u; float f; } va, vb, vc, vd;
        va.u = va0[m2] << 16;          // dim 2*m2
        vb.u = va0[m2] & 0xffff0000u;  // dim 2*m2+1
        vc.u = va1[m2] << 16;          // dim 8+2*m2
        vd.u = va1[m2] & 0xffff0000u;  // dim 8+2*m2+1
        const int d0 = 2 * m2, d1 = 2 * m2 + 1;
        os4[d0 >> 2][d0 & 3] = fmaf(os4[d0 >> 2][d0 & 3], al, e * va.f);
        os4[d1 >> 2][d1 & 3] = fmaf(os4[d1 >> 2][d1 & 3], al, e * vb.f);
        os4[(d0 + 8) >> 2][d0 & 3] = fmaf(os4[(d0 + 8) >> 2][d0 & 3], al, e * vc.f);
        os4[(d1 + 8) >> 2][d1 & 3] = fmaf(os4[(d1 + 8) >> 2][d1 & 3], al, e * vd.f);
      }
    };

    int k0s = q0 - 384;
    if (k0s >= 64) {
      uint4v ka0 = *(const uint4v*)(Kr + (size_t)k0s * 64);
      uint4v ka1 = *(const uint4v*)(Kr + (size_t)k0s * 64 + 8);
      uint4v va0 = *(const uint4v*)(Vr + (size_t)k0s * 64);
      uint4v va1 = *(const uint4v*)(Vr + (size_t)k0s * 64 + 8);
      while (true) {
        const int nxt = k0s - 128;
        uint4v kb0, kb1, vb0, vb1;
        if (nxt >= 64) {  // depth-1 prefetch: L2-hit latency hides under sproc
          kb0 = *(const uint4v*)(Kr + (size_t)nxt * 64);
          kb1 = *(const uint4v*)(Kr + (size_t)nxt * 64 + 8);
          vb0 = *(const uint4v*)(Vr + (size_t)nxt * 64);
          vb1 = *(const uint4v*)(Vr + (size_t)nxt * 64 + 8);
        }
        sproc(ka0, ka1, va0, va1);
        if (nxt < 64) break;
        ka0 = kb0; ka1 = kb1; va0 = vb0; va1 = vb1;
        k0s = nxt;
      }
    }

    // ---- merge strided state into dense state (once per block) -------------
    // scratch aliases K/Vt/P: every wave must be past its dense-tile LDS reads.
    __syncthreads();
    float* scr = (float*)smem + wave * (16 * 68);  // per-wave [16][68] f32
#pragma unroll
    for (int c = 0; c < 4; c++)
      *(f32x4*)&scr[l15 * 68 + quad * 16 + c * 4] = os4[c];
    asm volatile("s_waitcnt lgkmcnt(0)" ::: "memory");
    __builtin_amdgcn_wave_barrier();
#pragma unroll
    for (int r = 0; r < 4; r++) {
      const float ms_r = __shfl(ms, quad * 4 + r);
      const float ls_r = __shfl(ls, quad * 4 + r);
      const float M = fmaxf(mrun[r], ms_r);
      const float ea = __expf(mrun[r] - M);
      const float eb = __expf(ms_r - M);  // == 0 when no strided levels ran
      lsum[r] = lsum[r] * ea + ls_r * eb;
#pragma unroll
      for (int dt = 0; dt < 4; dt++)
        o[dt][r] = o[dt][r] * ea + scr[(quad * 4 + r) * 68 + dt * 16 + l15] * eb;
    }
  }

#pragma unroll
  for (int dt = 0; dt < 4; dt++) {
#pragma unroll
    for (int r = 0; r < 4; r++) {
      const int t = q0 + wl * 16 + quad * 4 + r;
      const int c = h * 64 + dt * 16 + l15;
      Y[(size_t)(b * 4096 + t) * 1024 + c] = f2b(o[dt][r] / lsum[r]);
    }
  }
}

// ---- launch -----------------------------------------------------------------
static const void* by_size(void* const* d_in, const int* in_sizes, int n_in,
                           int want, int fallback_idx) {
  for (int i = 0; i < n_in; i++)
    if (in_sizes[i] == want) return d_in[i];
  return d_in[fallback_idx];
}

extern "C" void kernel_launch(void* const* d_in, const int* in_sizes, int n_in,
                              void* d_out, int out_size, void* d_ws,
                              size_t ws_size, hipStream_t stream) {
  const float* x      = (const float*)by_size(d_in, in_sizes, n_in, 8388608, 0);
  const float* w_qkv  = (const float*)by_size(d_in, in_sizes, n_in, 3145728, 1);
  const float* b_qkv  = (const float*)by_size(d_in, in_sizes, n_in, 3072, 2);
  const float* w_proj = (const float*)by_size(d_in, in_sizes, n_in, 1048576, 3);
  const float* b_proj = (const float*)by_size(d_in, in_sizes, n_in, 1024, 4);
  float* out = (float*)d_out;                     // [2,4096,1024] f32
  char* ws = (char*)d_ws;
  ushort_t* wqkvT  = (ushort_t*)(ws);             //  6.3 MB bf16 [3072,1024]
  ushort_t* wprojT = (ushort_t*)(ws + 6291456);   //  2.1 MB bf16 [1024,1024]
  ushort_t* qb     = (ushort_t*)(ws + 8388608);   // 16.8 MB bf16 [B,H,T,D]
  ushort_t* kb     = (ushort_t*)(ws + 25165824);
  ushort_t* vb     = (ushort_t*)(ws + 41943040);
  ushort_t* yb     = (ushort_t*)(ws + 58720256);  // 16.8 MB bf16 [8192,1024]
  ushort_t* xb     = yb;  // x-bf16 aliases yb: dead before attention writes yb

  if (ws_size < 75497472) return;  // proven satisfied

  f32_to_b16<<<4096, 256, 0, stream>>>(x, xb);
  transpose_f2b<<<dim3(16, 48), 256, 0, stream>>>(w_qkv, wqkvT, 1024, 3072);
  transpose_f2b<<<dim3(16, 16), 256, 0, stream>>>(w_proj, wprojT, 1024, 1024);
  gemm_bt<0><<<dim3(24, 64), 256, 0, stream>>>(
      xb, wqkvT, b_qkv, qb, kb, vb, nullptr, 8192, 3072, 1024);
  sparse_attn<<<dim3(32, 16, 2), 512, 0, stream>>>(qb, kb, vb, yb);
  gemm_bt<1><<<dim3(8, 64), 256, 0, stream>>>(
      yb, wprojT, b_proj, nullptr, nullptr, nullptr, out, 8192, 1024, 1024);
}